// Round 9
// baseline (32.798 us; speedup 1.0000x reference)
//
#include <hip/hip_runtime.h>

#define B_ 4
#define N_ 256
#define T_ 16
#define F_ 128
#define H_ 256
#define BN_ (B_ * N_)  // 1024

// ---------------------------------------------------------------------------
// lp_prep: blocks 0..127  : hbar[bn][f] = mean_t nodefeat[bn][t][f]
//          blocks 128..143: W1T[k][h] = W1[h][k]   (LDS-tiled transpose)
// (round-3 version verbatim)
// ---------------------------------------------------------------------------
__global__ __launch_bounds__(1024) void lp_prep(const float* __restrict__ nf,
                                                const float* __restrict__ W1,
                                                float* __restrict__ hbar,
                                                float* __restrict__ W1T) {
    __shared__ float sT[64][65];
    const int tid = threadIdx.x;
    if (blockIdx.x < 128) {
        const int idx = blockIdx.x * 1024 + tid;   // bn*128 + f
        const int bn  = idx >> 7;
        const int f   = idx & 127;
        const float* src = nf + (size_t)bn * (T_ * F_) + f;
        float s = 0.f;
#pragma unroll
        for (int t = 0; t < T_; ++t) s += src[t * F_];
        hbar[idx] = s * (1.0f / 16.0f);
    } else {
        const int t  = blockIdx.x - 128;  // 0..15
        const int y0 = (t >> 2) * 64;     // h-tile base
        const int x0 = (t & 3) * 64;      // k-tile base
        const int ty = tid >> 6;          // 0..15
        const int tx = tid & 63;
#pragma unroll
        for (int r = 0; r < 4; ++r)
            sT[r * 16 + ty][tx] = W1[(size_t)(y0 + r * 16 + ty) * 256 + (x0 + tx)];
        __syncthreads();
#pragma unroll
        for (int r = 0; r < 4; ++r)
            W1T[(size_t)(x0 + r * 16 + ty) * 256 + (y0 + tx)] = sT[tx][r * 16 + ty];
    }
}

// ---------------------------------------------------------------------------
// lp_gemm: block = (8-node tile, h-half), 512 threads = (kq 0..3, hl 0..127).
// W1T loads lane-coalesced; hbar via wave-uniform s_load.
// Outputs: aT[tile4][h][4] (b1 folded), cT2[b][h/2][N][2]  (h-PAIR layout so
// k2 gets one b64 load per 2 h).
// ---------------------------------------------------------------------------
__global__ __launch_bounds__(512) void lp_gemm(const float* __restrict__ hbar,
                                               const float* __restrict__ W1T,
                                               const float* __restrict__ b1,
                                               float* __restrict__ aT,
                                               float* __restrict__ cT2) {
    __shared__ float red[16][4][128];  // [val][kq][hl] = 32 KB

    const int tile8 = blockIdx.x >> 1;        // 0..127 -> 8 nodes
    const int h0    = (blockIdx.x & 1) * 128; // h half
    const int bn0   = tile8 * 8;
    const int b     = bn0 >> 8;
    const int tid   = threadIdx.x;
    const int kq    = __builtin_amdgcn_readfirstlane(tid >> 7);  // 0..3
    const int hl    = tid & 127;
    const int h     = h0 + hl;

    const float* wA = W1T + (size_t)(kq * 32) * H_ + h;
    const float* wC = W1T + (size_t)(F_ + kq * 32) * H_ + h;
    const float* hb = hbar + (size_t)bn0 * F_ + kq * 32;  // wave-uniform base

    float acca[8] = {0.f, 0.f, 0.f, 0.f, 0.f, 0.f, 0.f, 0.f};
    float accc[8] = {0.f, 0.f, 0.f, 0.f, 0.f, 0.f, 0.f, 0.f};

#pragma unroll 4
    for (int kk = 0; kk < 32; ++kk) {
        const float wa = wA[(size_t)kk * H_];   // coalesced over lanes
        const float wc = wC[(size_t)kk * H_];
#pragma unroll
        for (int n = 0; n < 8; ++n) {
            const float hv = hb[n * F_ + kk];   // uniform -> s_load
            acca[n] = fmaf(hv, wa, acca[n]);
            accc[n] = fmaf(hv, wc, accc[n]);
        }
    }

#pragma unroll
    for (int n = 0; n < 8; ++n) {
        red[n][kq][hl]     = acca[n];
        red[8 + n][kq][hl] = accc[n];
    }
    __syncthreads();

    const int rv = tid >> 7;  // 0..3
#pragma unroll
    for (int i = 0; i < 4; ++i) {
        const int v = rv * 4 + i;  // 0..15
        const float s = (red[v][0][hl] + red[v][1][hl]) + (red[v][2][hl] + red[v][3][hl]);
        if (v < 8) {
            const int bn = bn0 + v;
            aT[((size_t)(bn >> 2) * H_ + h) * 4 + (bn & 3)] = s + b1[h];
        } else {
            const int n = v - 8;
            // cT2[b][h>>1][n0+n][h&1]
            cT2[(((size_t)b * (H_ / 2) + (h >> 1)) * N_ + ((bn0 & 255) + n)) * 2 + (h & 1)] = s;
        }
    }
}

// ---------------------------------------------------------------------------
// lp_k2 v4: relu(x) = (x+|x|)/2  =>
//   logits[i][j] = 0.5*( sum_h |a[i][h]+c[j][h]|*W2[h] + u_i + v_j ) + b2
// where u_i = sum_h a[i][h]W2[h] (prologue, shfl-reduced),
//       v_j = sum_h c[j][h]W2[h] (accumulated alongside the main loop).
// |x| folds into the fma as a free input modifier -> 2 VALU per (i,j,h).
// Grid 512 = 4b x 64 i-tiles(4) x 2 j-halves; 1024 thr = (ho 0..7, jl 0..127);
// __launch_bounds__(1024,8) -> 2 blocks/CU = 8 waves/SIMD.
// cT2 b64 loads: 1 load per 2 h, 512B/wave contiguous. a-pairs + W2 uniform.
// ---------------------------------------------------------------------------
__global__ __launch_bounds__(1024, 8) void lp_k2(const float* __restrict__ aT,
                                                 const float* __restrict__ cT2,
                                                 const float* __restrict__ W2,
                                                 const float* __restrict__ b2,
                                                 float* __restrict__ out) {
    __shared__ float pr[8][5][128];  // [ho][row0..3 | vacc][jl] = 20 KB
    __shared__ float swu[16];        // per-wave u partials

    const int bx    = blockIdx.x;    // 0..511
    const int b     = bx >> 7;
    const int rr    = bx & 127;
    const int it    = rr >> 1;       // 0..63 : i-tile of 4 rows
    const int jh    = rr & 1;        // j half
    const int i0    = it * 4;
    const int j0    = jh * 128;
    const int bn0   = b * N_ + i0;
    const int tile4 = bn0 >> 2;      // == the aligned 4-row tile

    const int tid = threadIdx.x;
    const float* atile = aT + (size_t)tile4 * (H_ * 4);  // [h][4], uniform base

    // ---- prologue: u_i = sum_h a[i][h]*W2[h], wave shfl-reduce ----
    {
        const int i  = tid >> 8;     // 0..3 (constant per wave)
        const int hs = tid & 255;    // lanes consecutive -> coalesced
        float pa = atile[hs * 4 + i] * W2[hs];
#pragma unroll
        for (int off = 32; off >= 1; off >>= 1)
            pa += __shfl_xor(pa, off, 64);
        if ((tid & 63) == 0) swu[tid >> 6] = pa;  // wave w: i = w>>2
    }

    const int ho  = tid >> 7;        // 0..7 (uniform per 2-wave group)
    const int jl  = tid & 127;
    const int hp0 = ho * 16;         // 16 h-pairs per chunk

    const float* cb   = cT2 + (((size_t)b * (H_ / 2) + hp0) * N_ + (j0 + jl)) * 2;
    const float* arow = atile + hp0 * 8;  // 8 floats per pair (2 h x 4 i)
    const float* w2p  = W2 + hp0 * 2;

    float acc0 = 0.f, acc1 = 0.f, acc2 = 0.f, acc3 = 0.f, vacc = 0.f;

#pragma unroll 4
    for (int p = 0; p < 16; ++p) {
        const float2 cc = *(const float2*)(cb + (size_t)p * (N_ * 2));  // coalesced b64
        const float4 aa = *(const float4*)(arow + p * 8);       // a[i0..3][2hp]   (s_load)
        const float4 ab = *(const float4*)(arow + p * 8 + 4);   // a[i0..3][2hp+1] (s_load)
        const float  w0 = w2p[p * 2];                           // s_load
        const float  w1 = w2p[p * 2 + 1];
        float x;
        x = aa.x + cc.x; acc0 = fmaf(__builtin_fabsf(x), w0, acc0);
        x = aa.y + cc.x; acc1 = fmaf(__builtin_fabsf(x), w0, acc1);
        x = aa.z + cc.x; acc2 = fmaf(__builtin_fabsf(x), w0, acc2);
        x = aa.w + cc.x; acc3 = fmaf(__builtin_fabsf(x), w0, acc3);
        x = ab.x + cc.y; acc0 = fmaf(__builtin_fabsf(x), w1, acc0);
        x = ab.y + cc.y; acc1 = fmaf(__builtin_fabsf(x), w1, acc1);
        x = ab.z + cc.y; acc2 = fmaf(__builtin_fabsf(x), w1, acc2);
        x = ab.w + cc.y; acc3 = fmaf(__builtin_fabsf(x), w1, acc3);
        vacc = fmaf(cc.x, w0, vacc);     // v_j partial (rank-1 term)
        vacc = fmaf(cc.y, w1, vacc);
    }

    pr[ho][0][jl] = acc0;
    pr[ho][1][jl] = acc1;
    pr[ho][2][jl] = acc2;
    pr[ho][3][jl] = acc3;
    pr[ho][4][jl] = vacc;
    __syncthreads();

    // ---- epilogue: 512 outputs (4 i x 128 j) ----
    if (tid < 512) {
        const int oi = tid >> 7;     // 0..3
        const int oj = tid & 127;
        float s = 0.f, v = 0.f;
#pragma unroll
        for (int o = 0; o < 8; ++o) {
            s += pr[o][oi][oj];
            v += pr[o][4][oj];
        }
        const float u = (swu[oi * 4 + 0] + swu[oi * 4 + 1]) +
                        (swu[oi * 4 + 2] + swu[oi * 4 + 3]);
        out[(size_t)(bn0 + oi) * N_ + (j0 + oj)] = 0.5f * (s + v + u) + b2[0];
    }
}

extern "C" void kernel_launch(void* const* d_in, const int* in_sizes, int n_in,
                              void* d_out, int out_size, void* d_ws, size_t ws_size,
                              hipStream_t stream) {
    const float* nodefeat = (const float*)d_in[0];  // [B,N,T,F]
    const float* W1       = (const float*)d_in[1];  // [H, 2F]
    const float* b1       = (const float*)d_in[2];  // [H]
    const float* W2       = (const float*)d_in[3];  // [1, H]
    const float* b2       = (const float*)d_in[4];  // [1]
    float* out = (float*)d_out;                     // [B,N,N]

    float* hbar = (float*)d_ws;                     // [1024][128]        = 512 KB
    float* W1T  = hbar + (size_t)BN_ * F_;          // [256][256]         = 256 KB
    float* aT   = W1T + 256 * 256;                  // [256 tiles][H][4]  = 1 MB
    float* cT2  = aT + (size_t)256 * H_ * 4;        // [B][H/2][N][2]     = 1 MB

    lp_prep<<<144, 1024, 0, stream>>>(nodefeat, W1, hbar, W1T);
    lp_gemm<<<256, 512, 0, stream>>>(hbar, W1T, b1, aT, cT2);
    lp_k2<<<512, 1024, 0, stream>>>(aT, cT2, W2, b2, out);
}

// Round 10
// 24.226 us; speedup vs baseline: 1.3538x; 1.3538x over previous
//
#include <hip/hip_runtime.h>

#define B_ 4
#define N_ 256
#define T_ 16
#define F_ 128
#define H_ 256
#define BN_ (B_ * N_)  // 1024

// ---------------------------------------------------------------------------
// lp_prep: blocks 0..127  : hbar[bn][f] = mean_t nodefeat[bn][t][f]
//          blocks 128..143: W1T[k][h] = W1[h][k]   (LDS-tiled transpose)
// (round-3 version verbatim)
// ---------------------------------------------------------------------------
__global__ __launch_bounds__(1024) void lp_prep(const float* __restrict__ nf,
                                                const float* __restrict__ W1,
                                                float* __restrict__ hbar,
                                                float* __restrict__ W1T) {
    __shared__ float sT[64][65];
    const int tid = threadIdx.x;
    if (blockIdx.x < 128) {
        const int idx = blockIdx.x * 1024 + tid;   // bn*128 + f
        const int bn  = idx >> 7;
        const int f   = idx & 127;
        const float* src = nf + (size_t)bn * (T_ * F_) + f;
        float s = 0.f;
#pragma unroll
        for (int t = 0; t < T_; ++t) s += src[t * F_];
        hbar[idx] = s * (1.0f / 16.0f);
    } else {
        const int t  = blockIdx.x - 128;  // 0..15
        const int y0 = (t >> 2) * 64;     // h-tile base
        const int x0 = (t & 3) * 64;      // k-tile base
        const int ty = tid >> 6;          // 0..15
        const int tx = tid & 63;
#pragma unroll
        for (int r = 0; r < 4; ++r)
            sT[r * 16 + ty][tx] = W1[(size_t)(y0 + r * 16 + ty) * 256 + (x0 + tx)];
        __syncthreads();
#pragma unroll
        for (int r = 0; r < 4; ++r)
            W1T[(size_t)(x0 + r * 16 + ty) * 256 + (y0 + tx)] = sT[tx][r * 16 + ty];
    }
}

// ---------------------------------------------------------------------------
// lp_gemm: block = (8-node tile, h-half), 512 threads = (kq 0..3, hl 0..127).
// W1T loads lane-coalesced; hbar via wave-uniform s_load.
// Outputs: aT[tile4][h][4] (b1 folded), cT[b][h][N].
// (round-3 version verbatim)
// ---------------------------------------------------------------------------
__global__ __launch_bounds__(512) void lp_gemm(const float* __restrict__ hbar,
                                               const float* __restrict__ W1T,
                                               const float* __restrict__ b1,
                                               float* __restrict__ aT,
                                               float* __restrict__ cT) {
    __shared__ float red[16][4][128];  // [val][kq][hl] = 32 KB

    const int tile8 = blockIdx.x >> 1;        // 0..127 -> 8 nodes
    const int h0    = (blockIdx.x & 1) * 128; // h half
    const int bn0   = tile8 * 8;
    const int b     = bn0 >> 8;
    const int tid   = threadIdx.x;
    const int kq    = __builtin_amdgcn_readfirstlane(tid >> 7);  // 0..3
    const int hl    = tid & 127;
    const int h     = h0 + hl;

    const float* wA = W1T + (size_t)(kq * 32) * H_ + h;
    const float* wC = W1T + (size_t)(F_ + kq * 32) * H_ + h;
    const float* hb = hbar + (size_t)bn0 * F_ + kq * 32;  // wave-uniform base

    float acca[8] = {0.f, 0.f, 0.f, 0.f, 0.f, 0.f, 0.f, 0.f};
    float accc[8] = {0.f, 0.f, 0.f, 0.f, 0.f, 0.f, 0.f, 0.f};

#pragma unroll 4
    for (int kk = 0; kk < 32; ++kk) {
        const float wa = wA[(size_t)kk * H_];   // coalesced over lanes
        const float wc = wC[(size_t)kk * H_];
#pragma unroll
        for (int n = 0; n < 8; ++n) {
            const float hv = hb[n * F_ + kk];   // uniform -> s_load
            acca[n] = fmaf(hv, wa, acca[n]);
            accc[n] = fmaf(hv, wc, accc[n]);
        }
    }

#pragma unroll
    for (int n = 0; n < 8; ++n) {
        red[n][kq][hl]     = acca[n];
        red[8 + n][kq][hl] = accc[n];
    }
    __syncthreads();

    const int rv = tid >> 7;  // 0..3
#pragma unroll
    for (int i = 0; i < 4; ++i) {
        const int v = rv * 4 + i;  // 0..15
        const float s = (red[v][0][hl] + red[v][1][hl]) + (red[v][2][hl] + red[v][3][hl]);
        if (v < 8) {
            const int bn = bn0 + v;
            aT[((size_t)(bn >> 2) * H_ + h) * 4 + (bn & 3)] = s + b1[h];
        } else {
            const int n = v - 8;
            cT[((size_t)b * H_ + h) * N_ + ((bn0 & 255) + n)] = s;
        }
    }
}

// ---------------------------------------------------------------------------
// lp_k2 v5: R7's inner core at 2 blocks/CU (32 waves/CU) for latency hiding.
// Grid 512 = 4 b x 32 i-tiles(8 rows) x 4 j-quarters(64 j).
// 1024 threads = (ho in 0..15 = 16-wide h-chunk, jl in 0..63).
// Per h-iter: 1 coalesced cT dword (256B/wave) + 2 uniform s_load_dwordx4
// a-pairs + 1 uniform W2 + 24 VALU. Per-block cT = 64 KB -> 32 MB total
// (same as R7). LDS pr[16][8][64] = 32 KB -> 2 blocks/CU. VGPR ~35 (no
// min-waves clamp; natural fit for 8 waves/SIMD).
// ---------------------------------------------------------------------------
__global__ __launch_bounds__(1024) void lp_k2(const float* __restrict__ aT,
                                              const float* __restrict__ cT,
                                              const float* __restrict__ W2,
                                              const float* __restrict__ b2,
                                              float* __restrict__ out) {
    __shared__ float pr[16][8][64];  // [ho][i][jl] = 32 KB

    const int bx  = blockIdx.x;      // 0..511
    const int b   = bx >> 7;         // 0..3
    const int rr  = bx & 127;
    const int it  = rr >> 2;         // 0..31 : i-tile of 8 rows
    const int jq  = rr & 3;          // j quarter
    const int i0  = it * 8;
    const int j0  = jq * 64;
    const int bn0 = b * N_ + i0;

    const int tid = threadIdx.x;
    const int ho  = __builtin_amdgcn_readfirstlane(tid >> 6);  // 0..15, wave-uniform
    const int jl  = tid & 63;

    const float* crow = cT + (size_t)b * (H_ * N_) + j0 + jl;
    const float* a0 = aT + (size_t)(bn0 >> 2) * (H_ * 4);      // uniform base
    const float* a1 = a0 + H_ * 4;
    const int h0 = ho * 16;

    float acc0 = 0.f, acc1 = 0.f, acc2 = 0.f, acc3 = 0.f;
    float acc4 = 0.f, acc5 = 0.f, acc6 = 0.f, acc7 = 0.f;

#pragma unroll 4
    for (int hh = 0; hh < 16; ++hh) {
        const int h = h0 + hh;
        const float  cj  = crow[(size_t)h * N_];           // coalesced over jl
        const float  w   = W2[h];                          // uniform -> s_load
        const float4 av0 = *(const float4*)(a0 + h * 4);   // uniform -> s_load
        const float4 av1 = *(const float4*)(a1 + h * 4);   // uniform -> s_load
        float x;
        x = av0.x + cj; acc0 = fmaf(fmaxf(x, 0.f), w, acc0);
        x = av0.y + cj; acc1 = fmaf(fmaxf(x, 0.f), w, acc1);
        x = av0.z + cj; acc2 = fmaf(fmaxf(x, 0.f), w, acc2);
        x = av0.w + cj; acc3 = fmaf(fmaxf(x, 0.f), w, acc3);
        x = av1.x + cj; acc4 = fmaf(fmaxf(x, 0.f), w, acc4);
        x = av1.y + cj; acc5 = fmaf(fmaxf(x, 0.f), w, acc5);
        x = av1.z + cj; acc6 = fmaf(fmaxf(x, 0.f), w, acc6);
        x = av1.w + cj; acc7 = fmaf(fmaxf(x, 0.f), w, acc7);
    }

    pr[ho][0][jl] = acc0;
    pr[ho][1][jl] = acc1;
    pr[ho][2][jl] = acc2;
    pr[ho][3][jl] = acc3;
    pr[ho][4][jl] = acc4;
    pr[ho][5][jl] = acc5;
    pr[ho][6][jl] = acc6;
    pr[ho][7][jl] = acc7;
    __syncthreads();

    // combine: 512 outputs (8 i x 64 j); 16 LDS reads each (2-way bank = free)
    if (tid < 512) {
        const int oi = tid >> 6;   // 0..7
        const int oj = tid & 63;
        float s = 0.f;
#pragma unroll
        for (int o = 0; o < 16; ++o) s += pr[o][oi][oj];
        out[(size_t)(bn0 + oi) * N_ + j0 + oj] = s + b2[0];
    }
}

extern "C" void kernel_launch(void* const* d_in, const int* in_sizes, int n_in,
                              void* d_out, int out_size, void* d_ws, size_t ws_size,
                              hipStream_t stream) {
    const float* nodefeat = (const float*)d_in[0];  // [B,N,T,F]
    const float* W1       = (const float*)d_in[1];  // [H, 2F]
    const float* b1       = (const float*)d_in[2];  // [H]
    const float* W2       = (const float*)d_in[3];  // [1, H]
    const float* b2       = (const float*)d_in[4];  // [1]
    float* out = (float*)d_out;                     // [B,N,N]

    float* hbar = (float*)d_ws;                     // [1024][128]        = 512 KB
    float* W1T  = hbar + (size_t)BN_ * F_;          // [256][256]         = 256 KB
    float* aT   = W1T + 256 * 256;                  // [256 tiles][H][4]  = 1 MB
    float* cT   = aT + (size_t)256 * H_ * 4;        // [B][H][N]          = 1 MB

    lp_prep<<<144, 1024, 0, stream>>>(nodefeat, W1, hbar, W1T);
    lp_gemm<<<256, 512, 0, stream>>>(hbar, W1T, b1, aT, cT);
    lp_k2<<<512, 1024, 0, stream>>>(aT, cT, W2, b2, out);
}